// Round 1
// baseline (1188.857 us; speedup 1.0000x reference)
//
#include <hip/hip_runtime.h>
#include <math.h>

// SineSPE: per (b,h):  C[L=2048, R=256] = A[L,1280] @ Bz[1280,256]
//   A[l, f*20+s]  = trig(pisig[h,f,s/2]*l + (isK?0:off[h,f,s/2])) * pos[b,l,h,f]
//                   (s even -> cos, s odd -> sin)
//   Bz[f*20+s, r] = z[b,h,f,s,r] * softplus(gains[h,f,s%10]) / 128
// Round 1: fp32 correctness baseline (VALU-bound ~550us roofline). MFMA next.

#define NH 8
#define NF 64
#define NK 10
#define NS 20          // 2K
#define NR 256
#define NB 4
#define NL 2048
#define KTOT (NF*NS)   // 1280
#define CHUNK 32
#define NCHUNK (KTOT/CHUNK)  // 40
#define LT 64          // l-tile per block

__global__ __launch_bounds__(256)
void spe_kernel(const float* __restrict__ queries,
                const float* __restrict__ keys,
                const float* __restrict__ z,
                const float* __restrict__ freqs,
                const float* __restrict__ offsets,
                const float* __restrict__ gains,
                float* __restrict__ out)
{
    const int tid = threadIdx.x;        // 256 threads
    const int l0  = blockIdx.x * LT;    // 32 l-tiles
    const int bh  = blockIdx.y;         // 32 = B*H
    const int b   = bh >> 3;
    const int h   = bh & 7;
    const int isK = blockIdx.z;         // 0 = qhat, 1 = khat

    __shared__ float s_pisig[NF*NK];    // 2*pi*sigmoid(freqs)/2
    __shared__ float s_off[NF*NK];      // offsets (0 for keys)
    __shared__ float s_gsc[NF*NK];      // softplus(gains)/128
    __shared__ float qs[LT][NF+1];      // pos tile, +1 pad (conflict-free col reads)
    __shared__ float As[CHUNK][LT];
    __shared__ float Bs[CHUNK][NR];

    // --- per-head tables (640 each) ---
    for (int i = tid; i < NF*NK; i += 256) {
        float fv  = freqs[h*NF*NK + i];
        float sig = 1.0f / (1.0f + expf(-fv));
        s_pisig[i] = 6.2831855f * (sig * 0.5f);   // matches ref: (2*pi*fr)
        s_off[i]   = isK ? 0.0f : offsets[h*NF*NK + i];
        s_gsc[i]   = log1pf(expf(gains[h*NF*NK + i])) * 0.0078125f; // /sqrt(R*F)=128
    }

    // --- stage pos tile [64 l][64 f] ---
    {
        const float* pos = isK ? keys : queries;
        const int row = tid >> 2;
        const int c0  = (tid & 3) * 16;
        const float* src = pos + ((size_t)((b*NL + l0 + row)*NH + h))*NF + c0;
        #pragma unroll
        for (int j = 0; j < 4; ++j) {
            const float4 v = *(const float4*)(src + j*4);
            const int c = c0 + j*4;
            qs[row][c+0] = v.x; qs[row][c+1] = v.y;
            qs[row][c+2] = v.z; qs[row][c+3] = v.w;
        }
    }
    __syncthreads();

    const int tx = tid & 15;   // col group: cols jj*64 + tx*4 + jc
    const int ty = tid >> 4;   // row group: rows ty*4 + i

    float acc[4][4][4];
    #pragma unroll
    for (int i = 0; i < 4; ++i)
        #pragma unroll
        for (int jj = 0; jj < 4; ++jj)
            #pragma unroll
            for (int jc = 0; jc < 4; ++jc) acc[i][jj][jc] = 0.0f;

    for (int ch = 0; ch < NCHUNK; ++ch) {
        const int fs0 = ch * CHUNK;

        // --- stage Bz chunk [32][256], fold gain scale ---
        #pragma unroll
        for (int i = 0; i < 8; ++i) {
            const int row = (tid >> 6) + i*4;           // 0..31
            const int col = (tid & 63) * 4;             // coalesced over r
            const int fs  = fs0 + row;
            const int f   = fs / NS;
            const int s   = fs - f*NS;
            const int km  = (s >= NK) ? (s - NK) : s;   // gains tiled, NOT interleaved
            const float sc = s_gsc[f*NK + km];
            const float4 v = *(const float4*)(z + (((size_t)((b*NH + h)*NF + f))*NS + s)*NR + col);
            float4 w; w.x = v.x*sc; w.y = v.y*sc; w.z = v.z*sc; w.w = v.w*sc;
            *(float4*)&Bs[row][col] = w;
        }

        // --- synthesize A chunk [32][64]: trig * pos ---
        #pragma unroll
        for (int i = 0; i < 8; ++i) {
            const int fsl = (tid >> 6) + i*4;           // 0..31
            const int ll  = tid & 63;
            const int fs  = fs0 + fsl;
            const int f   = fs / NS;
            const int s   = fs - f*NS;
            const int k   = s >> 1;                     // omega IS interleaved
            const float ph = s_pisig[f*NK + k] * (float)(l0 + ll) + s_off[f*NK + k];
            const float w  = (s & 1) ? sinf(ph) : cosf(ph);
            As[fsl][ll] = w * qs[ll][f];
        }
        __syncthreads();

        // --- FMA inner loop: 64x256 tile, thread = 4 rows x 16 cols ---
        #pragma unroll
        for (int fs = 0; fs < CHUNK; ++fs) {
            const float4 av = *(const float4*)&As[fs][ty*4];
            const float a0 = av.x, a1 = av.y, a2 = av.z, a3 = av.w;
            #pragma unroll
            for (int jj = 0; jj < 4; ++jj) {
                const float4 bv = *(const float4*)&Bs[fs][jj*64 + tx*4];
                acc[0][jj][0] += a0*bv.x; acc[0][jj][1] += a0*bv.y;
                acc[0][jj][2] += a0*bv.z; acc[0][jj][3] += a0*bv.w;
                acc[1][jj][0] += a1*bv.x; acc[1][jj][1] += a1*bv.y;
                acc[1][jj][2] += a1*bv.z; acc[1][jj][3] += a1*bv.w;
                acc[2][jj][0] += a2*bv.x; acc[2][jj][1] += a2*bv.y;
                acc[2][jj][2] += a2*bv.z; acc[2][jj][3] += a2*bv.w;
                acc[3][jj][0] += a3*bv.x; acc[3][jj][1] += a3*bv.y;
                acc[3][jj][2] += a3*bv.z; acc[3][jj][3] += a3*bv.w;
            }
        }
        __syncthreads();
    }

    // --- epilogue: qhat at offset 0, khat after B*L*H*R ---
    const size_t out_off = (size_t)isK * ((size_t)NB*NL*NH*NR);
    #pragma unroll
    for (int i = 0; i < 4; ++i) {
        const int l = l0 + ty*4 + i;
        float* dst = out + out_off + ((size_t)((b*NL + l)*NH + h))*NR;
        #pragma unroll
        for (int jj = 0; jj < 4; ++jj) {
            float4 v;
            v.x = acc[i][jj][0]; v.y = acc[i][jj][1];
            v.z = acc[i][jj][2]; v.w = acc[i][jj][3];
            *(float4*)(dst + jj*64 + tx*4) = v;
        }
    }
}

extern "C" void kernel_launch(void* const* d_in, const int* in_sizes, int n_in,
                              void* d_out, int out_size, void* d_ws, size_t ws_size,
                              hipStream_t stream) {
    const float* queries = (const float*)d_in[0];
    const float* keys    = (const float*)d_in[1];
    const float* z       = (const float*)d_in[2];
    const float* freqs   = (const float*)d_in[3];
    const float* offsets = (const float*)d_in[4];
    const float* gains   = (const float*)d_in[5];
    float* out = (float*)d_out;

    dim3 grid(NL/LT, NB*NH, 2);   // 32 l-tiles x 32 (b,h) x {q,k}
    spe_kernel<<<grid, 256, 0, stream>>>(queries, keys, z, freqs, offsets, gains, out);
}

// Round 2
// 298.065 us; speedup vs baseline: 3.9886x; 3.9886x over previous
//
#include <hip/hip_runtime.h>
#include <math.h>

// SineSPE via bf16 MFMA. Per (b,h,qk): C[2048,256] = A[2048,1280] @ B[1280,256]
//   A[l, fs] = trig(fs,l) * pos[l, fs/20] * softplus_gain(fs)/128   (gain folded into A)
//   B[fs, r] = z[b,h,fs,r]   (raw, bf16-cvt only)
// LDS holds both operands in FRAGMENT ORDER: each 16x16x32 frag = 1KB, lane-linear
// (lane reads lane*16 bytes -> conflict-free ds_read_b128 by construction).

#define NH 8
#define NF 64
#define NK 10
#define NR 256
#define NB 4
#define NL 2048
#define KTOT 1280
#define BM 128
#define BK 64
#define NCH (KTOT/BK)   // 20

typedef __attribute__((ext_vector_type(8))) short short8;
typedef __attribute__((ext_vector_type(4))) float f32x4;
typedef __attribute__((ext_vector_type(4))) unsigned int u32x4;

// LDS map (bytes)
#define OFF_B   0        // 32 KiB: [ks(2)][nf(16)] x 1KB frag images
#define OFF_A   32768    // 16 KiB: [ks(2)][mf(8)]  x 1KB frag images
#define OFF_POS 49152    // 16 KiB: bf16 pos_t[f(64)][m(128)]
#define OFF_FR  65536    // 2.5 KiB fp32 fr_rev[640]
#define OFF_OFS 68096    // 2.5 KiB fp32 off_rev[640]
#define OFF_GS  70656    // 2.5 KiB fp32 softplus(gains)/128 [640]
#define SMEM_SZ 73216    // 71.5 KiB -> 2 blocks/CU

static __device__ __forceinline__ unsigned short f2b(float f) {  // fp32->bf16 RNE
    unsigned x = __float_as_uint(f);
    return (unsigned short)((x + 0x7FFFu + ((x >> 16) & 1u)) >> 16);
}
static __device__ __forceinline__ unsigned int pk2(float a, float b) {
    return (unsigned int)f2b(a) | ((unsigned int)f2b(b) << 16);
}

__global__ __launch_bounds__(512, 4)
void spe_mfma(const float* __restrict__ queries,
              const float* __restrict__ keys,
              const float* __restrict__ z,
              const float* __restrict__ freqs,
              const float* __restrict__ offsets,
              const float* __restrict__ gains,
              float* __restrict__ out)
{
    __shared__ __attribute__((aligned(16))) unsigned char smem[SMEM_SZ];
    const int tid  = threadIdx.x;
    const int lane = tid & 63;
    const int l0   = blockIdx.x * BM;
    const int bh   = blockIdx.y;
    const int b = bh >> 3, h = bh & 7;
    const int isK  = blockIdx.z;

    float* ld_fr = (float*)(smem + OFF_FR);
    float* ld_of = (float*)(smem + OFF_OFS);
    float* ld_gs = (float*)(smem + OFF_GS);
    unsigned short* pos_t = (unsigned short*)(smem + OFF_POS);

    // ---- per-head tables (640 entries each) ----
    for (int i = tid; i < NF*NK; i += 512) {
        const float fv = freqs[h*NF*NK + i];
        ld_fr[i] = 0.5f / (1.0f + expf(-fv));                       // sigmoid/2 (revolutions/step)
        ld_of[i] = isK ? 0.0f : offsets[h*NF*NK + i] * 0.15915494309189535f; // rad -> rev
        ld_gs[i] = log1pf(expf(gains[h*NF*NK + i])) * 0.0078125f;   // softplus / sqrt(R*F)=128
    }
    // ---- pos tile, transposed bf16 [f][m] ----
    {
        const float* pos = isK ? keys : queries;
        #pragma unroll
        for (int i = 0; i < 4; ++i) {
            const int lrow = (tid >> 4) + 32*i;          // 0..127
            const int f0   = (tid & 15) * 4;
            const float4 v = *(const float4*)(pos + ((size_t)((b*NL + l0 + lrow)*NH + h))*NF + f0);
            pos_t[(f0+0)*BM + lrow] = f2b(v.x);
            pos_t[(f0+1)*BM + lrow] = f2b(v.y);
            pos_t[(f0+2)*BM + lrow] = f2b(v.z);
            pos_t[(f0+3)*BM + lrow] = f2b(v.w);
        }
    }
    __syncthreads();

    const int w  = tid >> 6;
    const int wm = w >> 2;      // 0..1  (wave tile 64x64 in 2x4 wave grid)
    const int wn = w & 3;       // 0..3

    f32x4 acc[4][4];
    #pragma unroll
    for (int mi = 0; mi < 4; ++mi)
        #pragma unroll
        for (int ni = 0; ni < 4; ++ni)
            acc[mi][ni] = (f32x4){0.f, 0.f, 0.f, 0.f};

    const float* zbh = z + (size_t)(b*NH + h) * ((size_t)KTOT*NR);

    for (int ch = 0; ch < NCH; ++ch) {
        const int fs0 = ch * BK;

        // ---- stage B: z -> bf16, fragment order. 4 tasks: r = lane-consecutive,
        //      8 k's per task -> one conflict-free ds_write_b128 each ----
        #pragma unroll
        for (int i = 0; i < 4; ++i) {
            const int tau  = tid + 512*i;
            const int r    = tau & 255;
            const int krun = tau >> 8;                 // 0..7
            const float* zp = zbh + (size_t)(fs0 + krun*8)*NR + r;
            u32x4 wv;
            #pragma unroll
            for (int jp = 0; jp < 4; ++jp)
                wv[jp] = pk2(zp[(2*jp)*NR], zp[(2*jp+1)*NR]);
            *(u32x4*)(smem + OFF_B + ((((krun>>2)*16) + (r>>4)) << 10)
                                   + ((((krun&3)*16) + (r&15)) << 4)) = wv;
        }

        // ---- stage A: trig*pos*gain -> bf16, fragment order. 2 tasks ----
        #pragma unroll
        for (int i = 0; i < 2; ++i) {
            const int tau  = tid + 512*i;
            const int m    = tau & 127;
            const int krun = tau >> 7;                 // 0..7
            const float lf = (float)(l0 + m);
            u32x4 wv;
            #pragma unroll
            for (int jp = 0; jp < 4; ++jp) {
                const int fs  = fs0 + krun*8 + 2*jp;   // even; (cos,sin) pair
                const int f   = (fs * 3277) >> 16;     // fs/20
                const int rem = fs - f*20;             // s for cos elem (even)
                const int kidx = f*10 + (rem >> 1);    // trig k (interleaved)
                const int gi   = f*10 + (rem >= 10 ? rem - 10 : rem); // gain idx (tiled); sin = gi+1
                const float x = __builtin_amdgcn_fractf(ld_of[kidx] + ld_fr[kidx]*lf);
                const float c = __builtin_amdgcn_cosf(x);
                const float s = __builtin_amdgcn_sinf(x);
                const float p = __uint_as_float(((unsigned)pos_t[f*BM + m]) << 16);
                wv[jp] = pk2(c * (p * ld_gs[gi]), s * (p * ld_gs[gi+1]));
            }
            *(u32x4*)(smem + OFF_A + ((((krun>>2)*8) + (m>>4)) << 10)
                                   + ((((krun&3)*16) + (m&15)) << 4)) = wv;
        }
        __syncthreads();

        // ---- MFMA: 2 k-steps x (4 mi x 4 ni), frags lane-linear ----
        #pragma unroll
        for (int ks = 0; ks < 2; ++ks) {
            short8 bf[4];
            #pragma unroll
            for (int ni = 0; ni < 4; ++ni)
                bf[ni] = *(const short8*)(smem + OFF_B + ((ks*16 + wn*4 + ni) << 10) + (lane << 4));
            #pragma unroll
            for (int mi = 0; mi < 4; ++mi) {
                const short8 af = *(const short8*)(smem + OFF_A + ((ks*8 + wm*4 + mi) << 10) + (lane << 4));
                #pragma unroll
                for (int ni = 0; ni < 4; ++ni)
                    acc[mi][ni] = __builtin_amdgcn_mfma_f32_16x16x32_bf16(af, bf[ni], acc[mi][ni], 0, 0, 0);
            }
        }
        __syncthreads();
    }

    // ---- epilogue: C/D layout col=lane&15, row=(lane>>4)*4+reg ----
    const size_t qk_off = (size_t)isK * ((size_t)NB*NL*NH*NR);
    const int row_l = (lane >> 4) * 4;
    const int col_r = lane & 15;
    #pragma unroll
    for (int mi = 0; mi < 4; ++mi) {
        const int lg = l0 + wm*64 + mi*16 + row_l;
        #pragma unroll
        for (int ni = 0; ni < 4; ++ni) {
            const int rg = wn*64 + ni*16 + col_r;
            const f32x4 v = acc[mi][ni];
            #pragma unroll
            for (int q = 0; q < 4; ++q)
                out[qk_off + ((size_t)((b*NL + lg + q)*NH + h))*NR + rg] = v[q];
        }
    }
}

extern "C" void kernel_launch(void* const* d_in, const int* in_sizes, int n_in,
                              void* d_out, int out_size, void* d_ws, size_t ws_size,
                              hipStream_t stream) {
    const float* queries = (const float*)d_in[0];
    const float* keys    = (const float*)d_in[1];
    const float* z       = (const float*)d_in[2];
    const float* freqs   = (const float*)d_in[3];
    const float* offsets = (const float*)d_in[4];
    const float* gains   = (const float*)d_in[5];
    float* out = (float*)d_out;

    dim3 grid(NL/BM, NB*NH, 2);   // 16 l-tiles x 32 (b,h) x {q,k} = 1024 blocks
    spe_mfma<<<grid, 512, 0, stream>>>(queries, keys, z, freqs, offsets, gains, out);
}

// Round 3
// 153.073 us; speedup vs baseline: 7.7666x; 1.9472x over previous
//
#include <hip/hip_runtime.h>
#include <math.h>

// SineSPE R3: prep kernel packs B = bf16(z * softplus(gain)/128) into d_ws in
// MFMA fragment order; main kernel streams B via global_load_lds (pure DMA),
// synthesizes A = bf16(trig * pos) on the fly, raw-barrier pipelined loop.
// Fallback to the validated R2 kernel if ws_size is too small.

#define NH 8
#define NF 64
#define NK 10
#define NR 256
#define NB 4
#define NL 2048
#define KTOT 1280
#define BM 128
#define BK 32
#define NCH (KTOT/BK)        // 40
#define NFRAG_B 16           // 16 x 1KB frag images per chunk (32k x 256r bf16)
#define WS_NEEDED ((size_t)NB*NH*NCH*NFRAG_B*1024)   // 20,971,520 B

typedef __attribute__((ext_vector_type(8))) short short8;
typedef __attribute__((ext_vector_type(4))) float f32x4;
typedef __attribute__((ext_vector_type(4))) unsigned int u32x4;

static __device__ __forceinline__ unsigned short f2b(float f) {  // fp32->bf16 RNE
    unsigned x = __float_as_uint(f);
    return (unsigned short)((x + 0x7FFFu + ((x >> 16) & 1u)) >> 16);
}
static __device__ __forceinline__ unsigned int pk2(float a, float b) {
    return (unsigned int)f2b(a) | ((unsigned int)f2b(b) << 16);
}
static __device__ __forceinline__ void gload_lds16(const void* g, void* l) {
    __builtin_amdgcn_global_load_lds(
        (const __attribute__((address_space(1))) unsigned int*)g,
        (__attribute__((address_space(3))) unsigned int*)l, 16, 0, 0);
}

// ---------------- prep: z -> bf16 frag-ordered Bpack (gains folded) ----------
__global__ __launch_bounds__(256)
void spe_prep(const float* __restrict__ z, const float* __restrict__ gains,
              unsigned char* __restrict__ bpack)
{
    __shared__ float s_g[NF*NK];
    const int ch  = blockIdx.x;     // 0..39
    const int bh  = blockIdx.y;     // 0..31
    const int h   = bh & 7;
    const int tid = threadIdx.x;
    for (int i = tid; i < NF*NK; i += 256)
        s_g[i] = log1pf(expf(gains[h*NF*NK + i])) * 0.0078125f;  // softplus/128
    __syncthreads();
    const float* zb = z + (size_t)bh * KTOT * NR;
    unsigned char* dst = bpack + ((size_t)(bh*NCH + ch) * NFRAG_B) * 1024;
    #pragma unroll
    for (int it = 0; it < 4; ++it) {
        const int s  = tid + 256*it;          // slot 0..1023
        const int fi = s >> 6;                // frag (r-group)
        const int l  = s & 63;                // frag lane
        const int r  = fi*16 + (l & 15);
        const int k0 = ch*BK + (l >> 4)*8;    // k-octet
        u32x4 wv;
        #pragma unroll
        for (int jp = 0; jp < 4; ++jp) {
            const int ka = k0 + 2*jp, kb = ka + 1;
            const int fa = (ka*3277) >> 16; int sa = ka - fa*20; if (sa >= NK) sa -= NK;
            const int fb = (kb*3277) >> 16; int sb = kb - fb*20; if (sb >= NK) sb -= NK;
            const float va = zb[(size_t)ka*NR + r] * s_g[fa*NK + sa];
            const float vb = zb[(size_t)kb*NR + r] * s_g[fb*NK + sb];
            wv[jp] = pk2(va, vb);
        }
        *(u32x4*)(dst + (size_t)s*16) = wv;
    }
}

// ---------------- main: pipelined MFMA ----------------
#define OFF_B0  0
#define OFF_B1  16384
#define OFF_A   32768
#define OFF_POS 40960          // 64 x 129 shorts = 16512 B
#define OFF_FR  57472
#define OFF_OF  60032
#define SMEM_SZ 62592

__global__ __launch_bounds__(512, 4)
void spe_main(const float* __restrict__ queries, const float* __restrict__ keys,
              const float* __restrict__ freqs, const float* __restrict__ offsets,
              const unsigned char* __restrict__ bpack, float* __restrict__ out)
{
    __shared__ __attribute__((aligned(16))) unsigned char smem[SMEM_SZ];
    const int tid  = threadIdx.x;
    const int lane = tid & 63;
    const int w    = tid >> 6;
    const int l0   = blockIdx.x * BM;
    const int bh   = blockIdx.y;
    const int b = bh >> 3, h = bh & 7;
    const int isK  = blockIdx.z;

    float* ld_fr = (float*)(smem + OFF_FR);
    float* ld_of = (float*)(smem + OFF_OF);
    unsigned short* pos_t = (unsigned short*)(smem + OFF_POS);

    for (int i = tid; i < NF*NK; i += 512) {
        const float fv = freqs[h*NF*NK + i];
        ld_fr[i] = 0.5f / (1.0f + expf(-fv));                                // rev/step
        ld_of[i] = isK ? 0.0f : offsets[h*NF*NK + i] * 0.15915494309189535f; // rad->rev
    }
    {   // pos tile -> bf16 transposed [f][m], stride 129
        const float* pos = isK ? keys : queries;
        #pragma unroll
        for (int i = 0; i < 4; ++i) {
            const int lrow = (tid >> 4) + 32*i;
            const int f0   = (tid & 15) * 4;
            const float4 v = *(const float4*)(pos + ((size_t)((b*NL + l0 + lrow)*NH + h))*NF + f0);
            pos_t[(f0+0)*129 + lrow] = f2b(v.x);
            pos_t[(f0+1)*129 + lrow] = f2b(v.y);
            pos_t[(f0+2)*129 + lrow] = f2b(v.z);
            pos_t[(f0+3)*129 + lrow] = f2b(v.w);
        }
    }
    __syncthreads();

    const unsigned char* bp = bpack + (size_t)bh * ((size_t)NCH*NFRAG_B*1024);
    const int fi0 = w*2;   // this wave's two B frags per chunk
    // prologue: issue chunk-0 B loads into B0
    gload_lds16(bp + (size_t)fi0*1024 + lane*16,       smem + OFF_B0 + (fi0  <<10));
    gload_lds16(bp + (size_t)(fi0+1)*1024 + lane*16,   smem + OFF_B0 + ((fi0+1)<<10));

    const int wm = w >> 2, wn = w & 3;
    f32x4 acc[4][4];
    #pragma unroll
    for (int mi = 0; mi < 4; ++mi)
        #pragma unroll
        for (int ni = 0; ni < 4; ++ni)
            acc[mi][ni] = (f32x4){0.f, 0.f, 0.f, 0.f};

    const int o_m = tid & 3;       // A-synth: k-octet
    const int m_m = tid >> 2;      //          m row 0..127
    const float lf = (float)(l0 + m_m);
    const int a_byte = (m_m >> 4)*1024 + (o_m*16 + (m_m & 15))*16;  // contiguous per wave

    for (int t = 0; t < NCH; ++t) {
        unsigned char* Bcur = smem + ((t & 1) ? OFF_B1 : OFF_B0);
        unsigned char* Bnxt = smem + ((t & 1) ? OFF_B0 : OFF_B1);

        // A-synth chunk t -> regs (overlaps other waves' MFMA(t-1))
        u32x4 wv;
        #pragma unroll
        for (int jp = 0; jp < 4; ++jp) {
            const int kk   = t*BK + o_m*8 + 2*jp;       // even k
            const int f    = (kk*3277) >> 16;           // kk/20
            const int srem = kk - f*20;
            const int kidx = f*NK + (srem >> 1);
            const float x  = __builtin_amdgcn_fractf(ld_of[kidx] + ld_fr[kidx]*lf);
            const float c  = __builtin_amdgcn_cosf(x);
            const float sn = __builtin_amdgcn_sinf(x);
            const float p  = __uint_as_float(((unsigned)pos_t[f*129 + m_m]) << 16);
            wv[jp] = pk2(c*p, sn*p);
        }

        asm volatile("s_waitcnt vmcnt(0)" ::: "memory");   // own B(t) loads landed
        __builtin_amdgcn_sched_barrier(0);
        __builtin_amdgcn_s_barrier();                      // (a) B(t) visible; MFMA(t-1) done

        if (t + 1 < NCH) {  // issue B(t+1) DMA; flies across both barriers + MFMA
            gload_lds16(bp + (size_t)((t+1)*NFRAG_B + fi0)*1024 + lane*16,
                        Bnxt + (fi0<<10));
            gload_lds16(bp + (size_t)((t+1)*NFRAG_B + fi0+1)*1024 + lane*16,
                        Bnxt + ((fi0+1)<<10));
        }

        *(u32x4*)(smem + OFF_A + a_byte) = wv;             // A(t) -> LDS
        asm volatile("s_waitcnt lgkmcnt(0)" ::: "memory");
        __builtin_amdgcn_sched_barrier(0);
        __builtin_amdgcn_s_barrier();                      // (b) A(t) visible

        short8 bf[4];
        #pragma unroll
        for (int ni = 0; ni < 4; ++ni)
            bf[ni] = *(const short8*)(Bcur + ((wn*4 + ni) << 10) + (lane << 4));
        #pragma unroll
        for (int mi = 0; mi < 4; ++mi) {
            const short8 af = *(const short8*)(smem + OFF_A + ((wm*4 + mi) << 10) + (lane << 4));
            #pragma unroll
            for (int ni = 0; ni < 4; ++ni)
                acc[mi][ni] = __builtin_amdgcn_mfma_f32_16x16x32_bf16(af, bf[ni], acc[mi][ni], 0, 0, 0);
        }
    }

    // epilogue: C/D layout col=lane&15, row=(lane>>4)*4+reg
    const size_t qk_off = (size_t)isK * ((size_t)NB*NL*NH*NR);
    const int row_l = (lane >> 4) * 4;
    const int col_r = lane & 15;
    #pragma unroll
    for (int mi = 0; mi < 4; ++mi) {
        const int lg = l0 + wm*64 + mi*16 + row_l;
        #pragma unroll
        for (int ni = 0; ni < 4; ++ni) {
            const int rg = wn*64 + ni*16 + col_r;
            const f32x4 v = acc[mi][ni];
            #pragma unroll
            for (int q = 0; q < 4; ++q)
                out[qk_off + ((size_t)((b*NL + lg + q)*NH + h))*NR + rg] = v[q];
        }
    }
}

// ---------------- fallback (validated R2 kernel) ----------------
#define FOFF_B   0
#define FOFF_A   32768
#define FOFF_POS 49152
#define FOFF_FR  65536
#define FOFF_OFS 68096
#define FOFF_GS  70656
#define FSMEM_SZ 73216

__global__ __launch_bounds__(512, 4)
void spe_mfma_fb(const float* __restrict__ queries, const float* __restrict__ keys,
                 const float* __restrict__ z, const float* __restrict__ freqs,
                 const float* __restrict__ offsets, const float* __restrict__ gains,
                 float* __restrict__ out)
{
    __shared__ __attribute__((aligned(16))) unsigned char smem[FSMEM_SZ];
    const int tid = threadIdx.x, lane = tid & 63;
    const int l0 = blockIdx.x * BM, bh = blockIdx.y;
    const int b = bh >> 3, h = bh & 7, isK = blockIdx.z;
    float* ld_fr = (float*)(smem + FOFF_FR);
    float* ld_of = (float*)(smem + FOFF_OFS);
    float* ld_gs = (float*)(smem + FOFF_GS);
    unsigned short* pos_t = (unsigned short*)(smem + FOFF_POS);
    for (int i = tid; i < NF*NK; i += 512) {
        const float fv = freqs[h*NF*NK + i];
        ld_fr[i] = 0.5f / (1.0f + expf(-fv));
        ld_of[i] = isK ? 0.0f : offsets[h*NF*NK + i] * 0.15915494309189535f;
        ld_gs[i] = log1pf(expf(gains[h*NF*NK + i])) * 0.0078125f;
    }
    {
        const float* pos = isK ? keys : queries;
        #pragma unroll
        for (int i = 0; i < 4; ++i) {
            const int lrow = (tid >> 4) + 32*i;
            const int f0 = (tid & 15) * 4;
            const float4 v = *(const float4*)(pos + ((size_t)((b*NL + l0 + lrow)*NH + h))*NF + f0);
            pos_t[(f0+0)*BM + lrow] = f2b(v.x); pos_t[(f0+1)*BM + lrow] = f2b(v.y);
            pos_t[(f0+2)*BM + lrow] = f2b(v.z); pos_t[(f0+3)*BM + lrow] = f2b(v.w);
        }
    }
    __syncthreads();
    const int w = tid >> 6, wm = w >> 2, wn = w & 3;
    f32x4 acc[4][4];
    #pragma unroll
    for (int mi = 0; mi < 4; ++mi)
        #pragma unroll
        for (int ni = 0; ni < 4; ++ni) acc[mi][ni] = (f32x4){0.f,0.f,0.f,0.f};
    const float* zbh = z + (size_t)(b*NH + h) * ((size_t)KTOT*NR);
    for (int ch = 0; ch < KTOT/64; ++ch) {
        const int fs0 = ch * 64;
        #pragma unroll
        for (int i = 0; i < 4; ++i) {
            const int tau = tid + 512*i, r = tau & 255, krun = tau >> 8;
            const float* zp = zbh + (size_t)(fs0 + krun*8)*NR + r;
            u32x4 wv2;
            #pragma unroll
            for (int jp = 0; jp < 4; ++jp) {
                const int fs = fs0 + krun*8 + 2*jp;
                const int f = (fs*3277) >> 16; const int rem = fs - f*20;
                const int km = (rem >= NK) ? rem - NK : rem;
                const int kn = ((rem+1) >= NK && (rem+1) < 2*NK) ? rem+1-NK : rem+1;
                const float sc0 = ld_gs[f*NK + km], sc1 = ld_gs[f*NK + (kn < NK ? kn : kn-NK)];
                wv2[jp] = pk2(zp[(2*jp)*NR]*sc0, zp[(2*jp+1)*NR]*sc1);
            }
            *(u32x4*)(smem + FOFF_B + ((((krun>>2)*16) + (r>>4)) << 10)
                                    + ((((krun&3)*16) + (r&15)) << 4)) = wv2;
        }
        #pragma unroll
        for (int i = 0; i < 2; ++i) {
            const int tau = tid + 512*i, m = tau & 127, krun = tau >> 7;
            const float lff = (float)(l0 + m);
            u32x4 wv2;
            #pragma unroll
            for (int jp = 0; jp < 4; ++jp) {
                const int fs = fs0 + krun*8 + 2*jp;
                const int f = (fs*3277) >> 16; const int rem = fs - f*20;
                const int kidx = f*NK + (rem >> 1);
                const float x = __builtin_amdgcn_fractf(ld_of[kidx] + ld_fr[kidx]*lff);
                const float c = __builtin_amdgcn_cosf(x), sn = __builtin_amdgcn_sinf(x);
                const float p = __uint_as_float(((unsigned)pos_t[f*BM + m]) << 16);
                wv2[jp] = pk2(c*p, sn*p);
            }
            *(u32x4*)(smem + FOFF_A + ((((krun>>2)*8) + (m>>4)) << 10)
                                    + ((((krun&3)*16) + (m&15)) << 4)) = wv2;
        }
        __syncthreads();
        #pragma unroll
        for (int ks = 0; ks < 2; ++ks) {
            short8 bf[4];
            #pragma unroll
            for (int ni = 0; ni < 4; ++ni)
                bf[ni] = *(const short8*)(smem + FOFF_B + ((ks*16 + wn*4 + ni) << 10) + (lane << 4));
            #pragma unroll
            for (int mi = 0; mi < 4; ++mi) {
                const short8 af = *(const short8*)(smem + FOFF_A + ((ks*8 + wm*4 + mi) << 10) + (lane << 4));
                #pragma unroll
                for (int ni = 0; ni < 4; ++ni)
                    acc[mi][ni] = __builtin_amdgcn_mfma_f32_16x16x32_bf16(af, bf[ni], acc[mi][ni], 0, 0, 0);
            }
        }
        __syncthreads();
    }
    const size_t qk_off = (size_t)isK * ((size_t)NB*NL*NH*NR);
    const int row_l = (lane >> 4) * 4, col_r = lane & 15;
    #pragma unroll
    for (int mi = 0; mi < 4; ++mi) {
        const int lg = l0 + wm*64 + mi*16 + row_l;
        #pragma unroll
        for (int ni = 0; ni < 4; ++ni) {
            const int rg = wn*64 + ni*16 + col_r;
            const f32x4 v = acc[mi][ni];
            #pragma unroll
            for (int q = 0; q < 4; ++q)
                out[qk_off + ((size_t)((b*NL + lg + q)*NH + h))*NR + rg] = v[q];
        }
    }
}

extern "C" void kernel_launch(void* const* d_in, const int* in_sizes, int n_in,
                              void* d_out, int out_size, void* d_ws, size_t ws_size,
                              hipStream_t stream) {
    const float* queries = (const float*)d_in[0];
    const float* keys    = (const float*)d_in[1];
    const float* z       = (const float*)d_in[2];
    const float* freqs   = (const float*)d_in[3];
    const float* offsets = (const float*)d_in[4];
    const float* gains   = (const float*)d_in[5];
    float* out = (float*)d_out;

    if (ws_size >= WS_NEEDED) {
        unsigned char* bpack = (unsigned char*)d_ws;
        spe_prep<<<dim3(NCH, NB*NH), 256, 0, stream>>>(z, gains, bpack);
        spe_main<<<dim3(NL/BM, NB*NH, 2), 512, 0, stream>>>(queries, keys, freqs, offsets, bpack, out);
    } else {
        spe_mfma_fb<<<dim3(NL/BM, NB*NH, 2), 512, 0, stream>>>(queries, keys, z, freqs, offsets, gains, out);
    }
}

// Round 4
// 133.648 us; speedup vs baseline: 8.8954x; 1.1453x over previous
//
#include <hip/hip_runtime.h>
#include <math.h>

// SineSPE R4: R3 structure + (a) A-synth(t+1) software-pipelined under MFMA(t)
// shadow, (b) conflict-free A-synth mapping (wave owns k-octet, rows=lane-consec),
// (c) pos_t stride 128 row-contiguous reads. Prep/Bpack/barriers unchanged.

#define NH 8
#define NF 64
#define NK 10
#define NR 256
#define NB 4
#define NL 2048
#define KTOT 1280
#define BM 128
#define BK 32
#define NCH (KTOT/BK)        // 40
#define NFRAG_B 16           // 16 x 1KB frag images per chunk (32k x 256r bf16)
#define WS_NEEDED ((size_t)NB*NH*NCH*NFRAG_B*1024)   // 20,971,520 B

typedef __attribute__((ext_vector_type(8))) short short8;
typedef __attribute__((ext_vector_type(4))) float f32x4;
typedef __attribute__((ext_vector_type(4))) unsigned int u32x4;

static __device__ __forceinline__ unsigned short f2b(float f) {  // fp32->bf16 RNE
    unsigned x = __float_as_uint(f);
    return (unsigned short)((x + 0x7FFFu + ((x >> 16) & 1u)) >> 16);
}
static __device__ __forceinline__ unsigned int pk2(float a, float b) {
    return (unsigned int)f2b(a) | ((unsigned int)f2b(b) << 16);
}
static __device__ __forceinline__ void gload_lds16(const void* g, void* l) {
    __builtin_amdgcn_global_load_lds(
        (const __attribute__((address_space(1))) unsigned int*)g,
        (__attribute__((address_space(3))) unsigned int*)l, 16, 0, 0);
}

// ---------------- prep: z -> bf16 frag-ordered Bpack (gains folded) ----------
__global__ __launch_bounds__(256)
void spe_prep(const float* __restrict__ z, const float* __restrict__ gains,
              unsigned char* __restrict__ bpack)
{
    __shared__ float s_g[NF*NK];
    const int ch  = blockIdx.x;     // 0..39
    const int bh  = blockIdx.y;     // 0..31
    const int h   = bh & 7;
    const int tid = threadIdx.x;
    for (int i = tid; i < NF*NK; i += 256)
        s_g[i] = log1pf(expf(gains[h*NF*NK + i])) * 0.0078125f;  // softplus/128
    __syncthreads();
    const float* zb = z + (size_t)bh * KTOT * NR;
    unsigned char* dst = bpack + ((size_t)(bh*NCH + ch) * NFRAG_B) * 1024;
    #pragma unroll
    for (int it = 0; it < 4; ++it) {
        const int s  = tid + 256*it;          // slot 0..1023
        const int fi = s >> 6;                // frag (r-group)
        const int l  = s & 63;                // frag lane
        const int r  = fi*16 + (l & 15);
        const int k0 = ch*BK + (l >> 4)*8;    // k-octet
        u32x4 wv;
        #pragma unroll
        for (int jp = 0; jp < 4; ++jp) {
            const int ka = k0 + 2*jp, kb = ka + 1;
            const int fa = (ka*3277) >> 16; int sa = ka - fa*20; if (sa >= NK) sa -= NK;
            const int fb = (kb*3277) >> 16; int sb = kb - fb*20; if (sb >= NK) sb -= NK;
            const float va = zb[(size_t)ka*NR + r] * s_g[fa*NK + sa];
            const float vb = zb[(size_t)kb*NR + r] * s_g[fb*NK + sb];
            wv[jp] = pk2(va, vb);
        }
        *(u32x4*)(dst + (size_t)s*16) = wv;
    }
}

// ---------------- main: pipelined MFMA ----------------
#define OFF_B0  0
#define OFF_B1  16384
#define OFF_A   32768          // 8 KiB
#define OFF_POS 40960          // 64 x 128 shorts = 16384 B
#define OFF_FR  57344
#define OFF_OF  59904
#define SMEM_SZ 62464

__global__ __launch_bounds__(512, 4)
void spe_main(const float* __restrict__ queries, const float* __restrict__ keys,
              const float* __restrict__ freqs, const float* __restrict__ offsets,
              const unsigned char* __restrict__ bpack, float* __restrict__ out)
{
    __shared__ __attribute__((aligned(16))) unsigned char smem[SMEM_SZ];
    const int tid  = threadIdx.x;
    const int lane = tid & 63;
    const int w    = tid >> 6;
    const int l0   = blockIdx.x * BM;
    const int bh   = blockIdx.y;
    const int b = bh >> 3, h = bh & 7;
    const int isK  = blockIdx.z;

    float* ld_fr = (float*)(smem + OFF_FR);
    float* ld_of = (float*)(smem + OFF_OF);
    unsigned short* pos_t = (unsigned short*)(smem + OFF_POS);

    for (int i = tid; i < NF*NK; i += 512) {
        const float fv = freqs[h*NF*NK + i];
        ld_fr[i] = 0.5f / (1.0f + expf(-fv));                                // rev/step
        ld_of[i] = isK ? 0.0f : offsets[h*NF*NK + i] * 0.15915494309189535f; // rad->rev
    }
    {   // pos tile -> bf16 transposed [f][m], stride 128
        const float* pos = isK ? keys : queries;
        const int r  = tid >> 2;           // 0..127
        const int f0 = (tid & 3) * 16;
        const float* src = pos + ((size_t)((b*NL + l0 + r)*NH + h))*NF + f0;
        #pragma unroll
        for (int j = 0; j < 4; ++j) {
            const float4 v = *(const float4*)(src + j*4);
            const int f = f0 + j*4;
            pos_t[(f+0)*BM + r] = f2b(v.x);
            pos_t[(f+1)*BM + r] = f2b(v.y);
            pos_t[(f+2)*BM + r] = f2b(v.z);
            pos_t[(f+3)*BM + r] = f2b(v.w);
        }
    }
    __syncthreads();

    const unsigned char* bp = bpack + (size_t)bh * ((size_t)NCH*NFRAG_B*1024);
    const int fi0 = w*2;   // this wave's two B frags per chunk
    // prologue: issue chunk-0 B loads into B0
    gload_lds16(bp + (size_t)fi0*1024 + lane*16,       smem + OFF_B0 + (fi0  <<10));
    gload_lds16(bp + (size_t)(fi0+1)*1024 + lane*16,   smem + OFF_B0 + ((fi0+1)<<10));

    const int wm = w >> 2, wn = w & 3;
    f32x4 acc[4][4];
    #pragma unroll
    for (int mi = 0; mi < 4; ++mi)
        #pragma unroll
        for (int ni = 0; ni < 4; ++ni)
            acc[mi][ni] = (f32x4){0.f, 0.f, 0.f, 0.f};

    // A-synth map: wave owns k-octet a_oct=w>>1; rows a_m=(w&1)*64+lane
    const int a_oct  = w >> 1;
    const int a_m    = ((w & 1) << 6) | lane;
    const float lf   = (float)(l0 + a_m);
    const int a_byte = (((w & 1)*4 + (lane >> 4)) << 10) + (a_oct << 8) + ((lane & 15) << 4);

    // synth A chunk t -> 4 packed dwords (one b128 frag slot)
    auto synthA = [&](int t) -> u32x4 {
        u32x4 wv;
        #pragma unroll
        for (int jp = 0; jp < 4; ++jp) {
            const int kk   = t*BK + a_oct*8 + 2*jp;     // even k
            const int f    = (kk*3277) >> 16;           // kk/20
            const int srem = kk - f*20;
            const int kidx = f*NK + (srem >> 1);
            const float x  = __builtin_amdgcn_fractf(ld_of[kidx] + ld_fr[kidx]*lf);
            const float c  = __builtin_amdgcn_cosf(x);
            const float sn = __builtin_amdgcn_sinf(x);
            const float p  = __uint_as_float(((unsigned)pos_t[f*BM + a_m]) << 16);
            wv[jp] = pk2(c*p, sn*p);
        }
        return wv;
    };

    u32x4 wv = synthA(0);   // overlaps chunk-0 DMA flight

    for (int t = 0; t < NCH; ++t) {
        unsigned char* Bcur = smem + ((t & 1) ? OFF_B1 : OFF_B0);
        unsigned char* Bnxt = smem + ((t & 1) ? OFF_B0 : OFF_B1);

        asm volatile("s_waitcnt vmcnt(0)" ::: "memory");   // own B(t) loads landed
        __builtin_amdgcn_sched_barrier(0);
        __builtin_amdgcn_s_barrier();                      // (a) B(t) visible; A(t-1)/B(t-1) readers done

        if (t + 1 < NCH) {  // issue B(t+1) DMA; flies across both barriers + MFMA
            gload_lds16(bp + (size_t)((t+1)*NFRAG_B + fi0)*1024 + lane*16,
                        Bnxt + (fi0<<10));
            gload_lds16(bp + (size_t)((t+1)*NFRAG_B + fi0+1)*1024 + lane*16,
                        Bnxt + ((fi0+1)<<10));
        }

        *(u32x4*)(smem + OFF_A + a_byte) = wv;             // A(t) -> LDS
        asm volatile("s_waitcnt lgkmcnt(0)" ::: "memory");
        __builtin_amdgcn_sched_barrier(0);
        __builtin_amdgcn_s_barrier();                      // (b) A(t) visible

        short8 bf[4];
        #pragma unroll
        for (int ni = 0; ni < 4; ++ni)
            bf[ni] = *(const short8*)(Bcur + ((wn*4 + ni) << 10) + (lane << 4));

        // A-synth(t+1) interleaves with MFMA(t) (VALU fills matrix-pipe shadow)
        if (t + 1 < NCH) wv = synthA(t + 1);

        #pragma unroll
        for (int mi = 0; mi < 4; ++mi) {
            const short8 af = *(const short8*)(smem + OFF_A + ((wm*4 + mi) << 10) + (lane << 4));
            #pragma unroll
            for (int ni = 0; ni < 4; ++ni)
                acc[mi][ni] = __builtin_amdgcn_mfma_f32_16x16x32_bf16(af, bf[ni], acc[mi][ni], 0, 0, 0);
        }
    }

    // epilogue: C/D layout col=lane&15, row=(lane>>4)*4+reg
    const size_t qk_off = (size_t)isK * ((size_t)NB*NL*NH*NR);
    const int row_l = (lane >> 4) * 4;
    const int col_r = lane & 15;
    #pragma unroll
    for (int mi = 0; mi < 4; ++mi) {
        const int lg = l0 + wm*64 + mi*16 + row_l;
        #pragma unroll
        for (int ni = 0; ni < 4; ++ni) {
            const int rg = wn*64 + ni*16 + col_r;
            const f32x4 v = acc[mi][ni];
            #pragma unroll
            for (int q = 0; q < 4; ++q)
                out[qk_off + ((size_t)((b*NL + lg + q)*NH + h))*NR + rg] = v[q];
        }
    }
}

// ---------------- fallback (validated R2 kernel) ----------------
#define FOFF_B   0
#define FOFF_A   32768
#define FOFF_POS 49152
#define FOFF_FR  65536
#define FOFF_OFS 68096
#define FOFF_GS  70656
#define FSMEM_SZ 73216

__global__ __launch_bounds__(512, 4)
void spe_mfma_fb(const float* __restrict__ queries, const float* __restrict__ keys,
                 const float* __restrict__ z, const float* __restrict__ freqs,
                 const float* __restrict__ offsets, const float* __restrict__ gains,
                 float* __restrict__ out)
{
    __shared__ __attribute__((aligned(16))) unsigned char smem[FSMEM_SZ];
    const int tid = threadIdx.x, lane = tid & 63;
    const int l0 = blockIdx.x * BM, bh = blockIdx.y;
    const int b = bh >> 3, h = bh & 7, isK = blockIdx.z;
    float* ld_fr = (float*)(smem + FOFF_FR);
    float* ld_of = (float*)(smem + FOFF_OFS);
    float* ld_gs = (float*)(smem + FOFF_GS);
    unsigned short* pos_t = (unsigned short*)(smem + FOFF_POS);
    for (int i = tid; i < NF*NK; i += 512) {
        const float fv = freqs[h*NF*NK + i];
        ld_fr[i] = 0.5f / (1.0f + expf(-fv));
        ld_of[i] = isK ? 0.0f : offsets[h*NF*NK + i] * 0.15915494309189535f;
        ld_gs[i] = log1pf(expf(gains[h*NF*NK + i])) * 0.0078125f;
    }
    {
        const float* pos = isK ? keys : queries;
        #pragma unroll
        for (int i = 0; i < 4; ++i) {
            const int lrow = (tid >> 4) + 32*i;
            const int f0 = (tid & 15) * 4;
            const float4 v = *(const float4*)(pos + ((size_t)((b*NL + l0 + lrow)*NH + h))*NF + f0);
            pos_t[(f0+0)*BM + lrow] = f2b(v.x); pos_t[(f0+1)*BM + lrow] = f2b(v.y);
            pos_t[(f0+2)*BM + lrow] = f2b(v.z); pos_t[(f0+3)*BM + lrow] = f2b(v.w);
        }
    }
    __syncthreads();
    const int w = tid >> 6, wm = w >> 2, wn = w & 3;
    f32x4 acc[4][4];
    #pragma unroll
    for (int mi = 0; mi < 4; ++mi)
        #pragma unroll
        for (int ni = 0; ni < 4; ++ni) acc[mi][ni] = (f32x4){0.f,0.f,0.f,0.f};
    const float* zbh = z + (size_t)(b*NH + h) * ((size_t)KTOT*NR);
    for (int ch = 0; ch < KTOT/64; ++ch) {
        const int fs0 = ch * 64;
        #pragma unroll
        for (int i = 0; i < 4; ++i) {
            const int tau = tid + 512*i, r = tau & 255, krun = tau >> 8;
            const float* zp = zbh + (size_t)(fs0 + krun*8)*NR + r;
            u32x4 wv2;
            #pragma unroll
            for (int jp = 0; jp < 4; ++jp) {
                const int fs = fs0 + krun*8 + 2*jp;
                const int f = (fs*3277) >> 16; const int rem = fs - f*20;
                const int km = (rem >= NK) ? rem - NK : rem;
                const int kn = ((rem+1) >= NK && (rem+1) < 2*NK) ? rem+1-NK : rem+1;
                const float sc0 = ld_gs[f*NK + km], sc1 = ld_gs[f*NK + (kn < NK ? kn : kn-NK)];
                wv2[jp] = pk2(zp[(2*jp)*NR]*sc0, zp[(2*jp+1)*NR]*sc1);
            }
            *(u32x4*)(smem + FOFF_B + ((((krun>>2)*16) + (r>>4)) << 10)
                                    + ((((krun&3)*16) + (r&15)) << 4)) = wv2;
        }
        #pragma unroll
        for (int i = 0; i < 2; ++i) {
            const int tau = tid + 512*i, m = tau & 127, krun = tau >> 7;
            const float lff = (float)(l0 + m);
            u32x4 wv2;
            #pragma unroll
            for (int jp = 0; jp < 4; ++jp) {
                const int fs = fs0 + krun*8 + 2*jp;
                const int f = (fs*3277) >> 16; const int rem = fs - f*20;
                const int kidx = f*NK + (rem >> 1);
                const float x = __builtin_amdgcn_fractf(ld_of[kidx] + ld_fr[kidx]*lff);
                const float c = __builtin_amdgcn_cosf(x), sn = __builtin_amdgcn_sinf(x);
                const float p = __uint_as_float(((unsigned)pos_t[f*BM + m]) << 16);
                wv2[jp] = pk2(c*p, sn*p);
            }
            *(u32x4*)(smem + FOFF_A + ((((krun>>2)*8) + (m>>4)) << 10)
                                    + ((((krun&3)*16) + (m&15)) << 4)) = wv2;
        }
        __syncthreads();
        #pragma unroll
        for (int ks = 0; ks < 2; ++ks) {
            short8 bf[4];
            #pragma unroll
            for (int ni = 0; ni < 4; ++ni)
                bf[ni] = *(const short8*)(smem + FOFF_B + ((ks*16 + wn*4 + ni) << 10) + (lane << 4));
            #pragma unroll
            for (int mi = 0; mi < 4; ++mi) {
                const short8 af = *(const short8*)(smem + FOFF_A + ((ks*8 + wm*4 + mi) << 10) + (lane << 4));
                #pragma unroll
                for (int ni = 0; ni < 4; ++ni)
                    acc[mi][ni] = __builtin_amdgcn_mfma_f32_16x16x32_bf16(af, bf[ni], acc[mi][ni], 0, 0, 0);
            }
        }
        __syncthreads();
    }
    const size_t qk_off = (size_t)isK * ((size_t)NB*NL*NH*NR);
    const int row_l = (lane >> 4) * 4, col_r = lane & 15;
    #pragma unroll
    for (int mi = 0; mi < 4; ++mi) {
        const int lg = l0 + wm*64 + mi*16 + row_l;
        #pragma unroll
        for (int ni = 0; ni < 4; ++ni) {
            const int rg = wn*64 + ni*16 + col_r;
            const f32x4 v = acc[mi][ni];
            #pragma unroll
            for (int q = 0; q < 4; ++q)
                out[qk_off + ((size_t)((b*NL + lg + q)*NH + h))*NR + rg] = v[q];
        }
    }
}

extern "C" void kernel_launch(void* const* d_in, const int* in_sizes, int n_in,
                              void* d_out, int out_size, void* d_ws, size_t ws_size,
                              hipStream_t stream) {
    const float* queries = (const float*)d_in[0];
    const float* keys    = (const float*)d_in[1];
    const float* z       = (const float*)d_in[2];
    const float* freqs   = (const float*)d_in[3];
    const float* offsets = (const float*)d_in[4];
    const float* gains   = (const float*)d_in[5];
    float* out = (float*)d_out;

    if (ws_size >= WS_NEEDED) {
        unsigned char* bpack = (unsigned char*)d_ws;
        spe_prep<<<dim3(NCH, NB*NH), 256, 0, stream>>>(z, gains, bpack);
        spe_main<<<dim3(NL/BM, NB*NH, 2), 512, 0, stream>>>(queries, keys, freqs, offsets, bpack, out);
    } else {
        spe_mfma_fb<<<dim3(NL/BM, NB*NH, 2), 512, 0, stream>>>(queries, keys, z, freqs, offsets, gains, out);
    }
}

// Round 5
// 126.078 us; speedup vs baseline: 9.4295x; 1.0600x over previous
//
#include <hip/hip_runtime.h>
#include <math.h>

// SineSPE R5: q/k merged per block (rows 0-63=q, 64-127=k of same l-range).
// A-synth: k-trig via fract/cos/sin, q-trig by offset-ROTATION (4 FMA, no trans);
// packing via v_cvt_pk_bf16_f32; A-frag region XOR-swizzled (4-way min writes).
// Prep/Bpack, DMA-prefetch barrier skeleton, epilogue unchanged from R4.

#define NH 8
#define NF 64
#define NK 10
#define NR 256
#define NB 4
#define NL 2048
#define KTOT 1280
#define BM 128               // 64 q-rows + 64 k-rows
#define BK 32
#define NCH (KTOT/BK)        // 40
#define NFRAG_B 16
#define WS_NEEDED ((size_t)NB*NH*NCH*NFRAG_B*1024)   // 20,971,520 B

typedef __attribute__((ext_vector_type(8))) short short8;
typedef __attribute__((ext_vector_type(4))) float f32x4;
typedef __attribute__((ext_vector_type(4))) unsigned int u32x4;
typedef __attribute__((ext_vector_type(2))) unsigned int u32x2;

static __device__ __forceinline__ unsigned short f2b(float f) {  // fp32->bf16 RNE
    unsigned x = __float_as_uint(f);
    return (unsigned short)((x + 0x7FFFu + ((x >> 16) & 1u)) >> 16);
}
static __device__ __forceinline__ unsigned int pk2(float a, float b) {
    return (unsigned int)f2b(a) | ((unsigned int)f2b(b) << 16);
}
static __device__ __forceinline__ unsigned int cvtpk(float lo, float hi) {
    unsigned int r;
    asm("v_cvt_pk_bf16_f32 %0, %1, %2" : "=v"(r) : "v"(lo), "v"(hi));
    return r;
}
static __device__ __forceinline__ void gload_lds16(const void* g, void* l) {
    __builtin_amdgcn_global_load_lds(
        (const __attribute__((address_space(1))) unsigned int*)g,
        (__attribute__((address_space(3))) unsigned int*)l, 16, 0, 0);
}

// ---------------- prep: z -> bf16 frag-ordered Bpack (gains folded) ----------
__global__ __launch_bounds__(256)
void spe_prep(const float* __restrict__ z, const float* __restrict__ gains,
              unsigned char* __restrict__ bpack)
{
    __shared__ float s_g[NF*NK];
    const int ch  = blockIdx.x;
    const int bh  = blockIdx.y;
    const int h   = bh & 7;
    const int tid = threadIdx.x;
    for (int i = tid; i < NF*NK; i += 256)
        s_g[i] = log1pf(expf(gains[h*NF*NK + i])) * 0.0078125f;  // softplus/128
    __syncthreads();
    const float* zb = z + (size_t)bh * KTOT * NR;
    unsigned char* dst = bpack + ((size_t)(bh*NCH + ch) * NFRAG_B) * 1024;
    #pragma unroll
    for (int it = 0; it < 4; ++it) {
        const int s  = tid + 256*it;
        const int fi = s >> 6;
        const int l  = s & 63;
        const int r  = fi*16 + (l & 15);
        const int k0 = ch*BK + (l >> 4)*8;
        u32x4 wv;
        #pragma unroll
        for (int jp = 0; jp < 4; ++jp) {
            const int ka = k0 + 2*jp, kb = ka + 1;
            const int fa = (ka*3277) >> 16; int sa = ka - fa*20; if (sa >= NK) sa -= NK;
            const int fb = (kb*3277) >> 16; int sb = kb - fb*20; if (sb >= NK) sb -= NK;
            const float va = zb[(size_t)ka*NR + r] * s_g[fa*NK + sa];
            const float vb = zb[(size_t)kb*NR + r] * s_g[fb*NK + sb];
            wv[jp] = pk2(va, vb);
        }
        *(u32x4*)(dst + (size_t)s*16) = wv;
    }
}

// ---------------- main ----------------
#define OFF_B0  0
#define OFF_B1  16384
#define OFF_A   32768          // 8 KiB: frags 0-3 q-rows, 4-7 k-rows (XOR-swizzled)
#define OFF_POS 40960          // [2 qk][64 f][64 rows] bf16 = 16384 B
#define OFF_FR  57344          // 640 f32
#define OFF_CO  59904          // 640 f32
#define OFF_SO  62464          // 640 f32
#define SMEM_SZ 65024          // 63.5 KiB -> 2 blocks/CU

__global__ __launch_bounds__(512, 4)
void spe_main(const float* __restrict__ queries, const float* __restrict__ keys,
              const float* __restrict__ freqs, const float* __restrict__ offsets,
              const unsigned char* __restrict__ bpack, float* __restrict__ out)
{
    __shared__ __attribute__((aligned(16))) unsigned char smem[SMEM_SZ];
    const int tid  = threadIdx.x;
    const int lane = tid & 63;
    const int w    = tid >> 6;
    const int l0   = blockIdx.x * 64;       // 64 l-rows per block (q AND k)
    const int bh   = blockIdx.y;
    const int b = bh >> 3, h = bh & 7;

    float* ld_fr = (float*)(smem + OFF_FR);
    float* ld_co = (float*)(smem + OFF_CO);
    float* ld_so = (float*)(smem + OFF_SO);
    unsigned short* pos_t = (unsigned short*)(smem + OFF_POS);

    for (int i = tid; i < NF*NK; i += 512) {
        const float fv = freqs[h*NF*NK + i];
        ld_fr[i] = 0.5f / (1.0f + expf(-fv));                                // rev/step
        const float xo = __builtin_amdgcn_fractf(offsets[h*NF*NK + i] * 0.15915494309189535f);
        ld_co[i] = __builtin_amdgcn_cosf(xo);
        ld_so[i] = __builtin_amdgcn_sinf(xo);
    }
    {   // pos tiles -> bf16 transposed [qk][f][64]
        const int r  = tid >> 2;            // 0..127: <64 q-row, >=64 k-row
        const int f0 = (tid & 3) * 16;
        const int rl = r & 63;
        const float* src = (r < 64)
            ? queries + ((size_t)((b*NL + l0 + rl)*NH + h))*NF + f0
            : keys    + ((size_t)((b*NL + l0 + rl)*NH + h))*NF + f0;
        unsigned short* pdst = pos_t + ((r >> 6) << 12);
        #pragma unroll
        for (int j = 0; j < 4; ++j) {
            const float4 v = *(const float4*)(src + j*4);
            const int f = f0 + j*4;
            pdst[(f+0)*64 + rl] = f2b(v.x);
            pdst[(f+1)*64 + rl] = f2b(v.y);
            pdst[(f+2)*64 + rl] = f2b(v.z);
            pdst[(f+3)*64 + rl] = f2b(v.w);
        }
    }
    __syncthreads();

    const unsigned char* bp = bpack + (size_t)bh * ((size_t)NCH*NFRAG_B*1024);
    const int fi0 = w*2;
    gload_lds16(bp + (size_t)fi0*1024 + lane*16,       smem + OFF_B0 + (fi0  <<10));
    gload_lds16(bp + (size_t)(fi0+1)*1024 + lane*16,   smem + OFF_B0 + ((fi0+1)<<10));

    const int wm = w >> 2, wn = w & 3;      // wm=0 -> q-half, wm=1 -> k-half
    f32x4 acc[4][4];
    #pragma unroll
    for (int mi = 0; mi < 4; ++mi)
        #pragma unroll
        for (int ni = 0; ni < 4; ++ni)
            acc[mi][ni] = (f32x4){0.f, 0.f, 0.f, 0.f};

    // A-synth map: rq = tid&63, oct = (tid>>6)&3, half = tid>>8 (2 pair-sites)
    const int rq   = tid & 63;
    const int oct  = (tid >> 6) & 3;
    const int half = tid >> 8;
    const float lf = (float)(l0 + rq);
    const unsigned short* posq = pos_t;
    const unsigned short* posk = pos_t + 4096;
    // logical A offsets (q-frag rq>>4, k-frag 4+(rq>>4)); swizzle: ^ (frag&3)<<5
    const int a_log_q = ((rq >> 4) << 10) + ((oct*16 + (rq & 15)) << 4) + (half << 3);
    const int aw_q = a_log_q ^ (((rq >> 4) & 3) << 5);
    const int aw_k = (a_log_q + 4096) ^ (((rq >> 4) & 3) << 5);

    auto synthA = [&](int t, u32x2& q01, u32x2& k01) {
        #pragma unroll
        for (int p = 0; p < 2; ++p) {
            const int kk   = t*BK + oct*8 + (half*2 + p)*2;   // even k
            const int f    = (kk*3277) >> 16;                 // kk/20
            const int srem = kk - f*20;
            const int kidx = f*NK + (srem >> 1);
            const float x  = __builtin_amdgcn_fractf(ld_fr[kidx] * lf);
            const float ck = __builtin_amdgcn_cosf(x);
            const float sk = __builtin_amdgcn_sinf(x);
            const float co = ld_co[kidx], so = ld_so[kidx];
            const float cq = ck*co - sk*so;                   // rotate by offset
            const float sq = sk*co + ck*so;
            const float pq = __uint_as_float(((unsigned)posq[f*64 + rq]) << 16);
            const float pk = __uint_as_float(((unsigned)posk[f*64 + rq]) << 16);
            q01[p] = cvtpk(cq*pq, sq*pq);
            k01[p] = cvtpk(ck*pk, sk*pk);
        }
    };

    u32x2 q01, k01;
    synthA(0, q01, k01);   // overlaps chunk-0 DMA flight

    for (int t = 0; t < NCH; ++t) {
        unsigned char* Bcur = smem + ((t & 1) ? OFF_B1 : OFF_B0);
        unsigned char* Bnxt = smem + ((t & 1) ? OFF_B0 : OFF_B1);

        asm volatile("s_waitcnt vmcnt(0)" ::: "memory");
        __builtin_amdgcn_sched_barrier(0);
        __builtin_amdgcn_s_barrier();                      // B(t) visible; prev readers done

        if (t + 1 < NCH) {
            gload_lds16(bp + (size_t)((t+1)*NFRAG_B + fi0)*1024 + lane*16,
                        Bnxt + (fi0<<10));
            gload_lds16(bp + (size_t)((t+1)*NFRAG_B + fi0+1)*1024 + lane*16,
                        Bnxt + ((fi0+1)<<10));
        }

        *(u32x2*)(smem + OFF_A + aw_q) = q01;              // A(t) -> LDS (swizzled)
        *(u32x2*)(smem + OFF_A + aw_k) = k01;
        asm volatile("s_waitcnt lgkmcnt(0)" ::: "memory");
        __builtin_amdgcn_sched_barrier(0);
        __builtin_amdgcn_s_barrier();                      // A(t) visible

        short8 bf[4];
        #pragma unroll
        for (int ni = 0; ni < 4; ++ni)
            bf[ni] = *(const short8*)(Bcur + ((wn*4 + ni) << 10) + (lane << 4));

        if (t + 1 < NCH) synthA(t + 1, q01, k01);          // VALU under MFMA shadow

        #pragma unroll
        for (int mi = 0; mi < 4; ++mi) {
            const int g    = wm*4 + mi;
            const int aoff = (g << 10) + (lane << 4);
            const short8 af = *(const short8*)(smem + OFF_A + (aoff ^ ((g & 3) << 5)));
            #pragma unroll
            for (int ni = 0; ni < 4; ++ni)
                acc[mi][ni] = __builtin_amdgcn_mfma_f32_16x16x32_bf16(af, bf[ni], acc[mi][ni], 0, 0, 0);
        }
    }

    // epilogue: wm selects q/k output; C/D layout col=lane&15, row=(lane>>4)*4+reg
    const size_t qk_off = (size_t)wm * ((size_t)NB*NL*NH*NR);
    const int row_l = (lane >> 4) * 4;
    const int col_r = lane & 15;
    #pragma unroll
    for (int mi = 0; mi < 4; ++mi) {
        const int lg = l0 + mi*16 + row_l;
        #pragma unroll
        for (int ni = 0; ni < 4; ++ni) {
            const int rg = wn*64 + ni*16 + col_r;
            const f32x4 v = acc[mi][ni];
            #pragma unroll
            for (int q = 0; q < 4; ++q)
                out[qk_off + ((size_t)((b*NL + lg + q)*NH + h))*NR + rg] = v[q];
        }
    }
}

// ---------------- fallback (validated R2 kernel) ----------------
#define FOFF_B   0
#define FOFF_A   32768
#define FOFF_POS 49152
#define FOFF_FR  65536
#define FOFF_OFS 68096
#define FOFF_GS  70656
#define FSMEM_SZ 73216

__global__ __launch_bounds__(512, 4)
void spe_mfma_fb(const float* __restrict__ queries, const float* __restrict__ keys,
                 const float* __restrict__ z, const float* __restrict__ freqs,
                 const float* __restrict__ offsets, const float* __restrict__ gains,
                 float* __restrict__ out)
{
    __shared__ __attribute__((aligned(16))) unsigned char smem[FSMEM_SZ];
    const int tid = threadIdx.x, lane = tid & 63;
    const int l0 = blockIdx.x * BM, bh = blockIdx.y;
    const int b = bh >> 3, h = bh & 7, isK = blockIdx.z;
    float* ld_fr = (float*)(smem + FOFF_FR);
    float* ld_of = (float*)(smem + FOFF_OFS);
    float* ld_gs = (float*)(smem + FOFF_GS);
    unsigned short* pos_t = (unsigned short*)(smem + FOFF_POS);
    for (int i = tid; i < NF*NK; i += 512) {
        const float fv = freqs[h*NF*NK + i];
        ld_fr[i] = 0.5f / (1.0f + expf(-fv));
        ld_of[i] = isK ? 0.0f : offsets[h*NF*NK + i] * 0.15915494309189535f;
        ld_gs[i] = log1pf(expf(gains[h*NF*NK + i])) * 0.0078125f;
    }
    {
        const float* pos = isK ? keys : queries;
        #pragma unroll
        for (int i = 0; i < 4; ++i) {
            const int lrow = (tid >> 4) + 32*i;
            const int f0 = (tid & 15) * 4;
            const float4 v = *(const float4*)(pos + ((size_t)((b*NL + l0 + lrow)*NH + h))*NF + f0);
            pos_t[(f0+0)*BM + lrow] = f2b(v.x); pos_t[(f0+1)*BM + lrow] = f2b(v.y);
            pos_t[(f0+2)*BM + lrow] = f2b(v.z); pos_t[(f0+3)*BM + lrow] = f2b(v.w);
        }
    }
    __syncthreads();
    const int w = tid >> 6, wm = w >> 2, wn = w & 3;
    f32x4 acc[4][4];
    #pragma unroll
    for (int mi = 0; mi < 4; ++mi)
        #pragma unroll
        for (int ni = 0; ni < 4; ++ni) acc[mi][ni] = (f32x4){0.f,0.f,0.f,0.f};
    const float* zbh = z + (size_t)(b*NH + h) * ((size_t)KTOT*NR);
    for (int ch = 0; ch < KTOT/64; ++ch) {
        const int fs0 = ch * 64;
        #pragma unroll
        for (int i = 0; i < 4; ++i) {
            const int tau = tid + 512*i, r = tau & 255, krun = tau >> 8;
            const float* zp = zbh + (size_t)(fs0 + krun*8)*NR + r;
            u32x4 wv2;
            #pragma unroll
            for (int jp = 0; jp < 4; ++jp) {
                const int fs = fs0 + krun*8 + 2*jp;
                const int f = (fs*3277) >> 16; const int rem = fs - f*20;
                const int km = (rem >= NK) ? rem - NK : rem;
                const int kn = ((rem+1) >= NK && (rem+1) < 2*NK) ? rem+1-NK : rem+1;
                const float sc0 = ld_gs[f*NK + km], sc1 = ld_gs[f*NK + (kn < NK ? kn : kn-NK)];
                wv2[jp] = pk2(zp[(2*jp)*NR]*sc0, zp[(2*jp+1)*NR]*sc1);
            }
            *(u32x4*)(smem + FOFF_B + ((((krun>>2)*16) + (r>>4)) << 10)
                                    + ((((krun&3)*16) + (r&15)) << 4)) = wv2;
        }
        #pragma unroll
        for (int i = 0; i < 2; ++i) {
            const int tau = tid + 512*i, m = tau & 127, krun = tau >> 7;
            const float lff = (float)(l0 + m);
            u32x4 wv2;
            #pragma unroll
            for (int jp = 0; jp < 4; ++jp) {
                const int fs = fs0 + krun*8 + 2*jp;
                const int f = (fs*3277) >> 16; const int rem = fs - f*20;
                const int kidx = f*NK + (rem >> 1);
                const float x = __builtin_amdgcn_fractf(ld_of[kidx] + ld_fr[kidx]*lff);
                const float c = __builtin_amdgcn_cosf(x), sn = __builtin_amdgcn_sinf(x);
                const float p = __uint_as_float(((unsigned)pos_t[f*BM + m]) << 16);
                wv2[jp] = pk2(c*p, sn*p);
            }
            *(u32x4*)(smem + FOFF_A + ((((krun>>2)*8) + (m>>4)) << 10)
                                    + ((((krun&3)*16) + (m&15)) << 4)) = wv2;
        }
        __syncthreads();
        #pragma unroll
        for (int ks = 0; ks < 2; ++ks) {
            short8 bf[4];
            #pragma unroll
            for (int ni = 0; ni < 4; ++ni)
                bf[ni] = *(const short8*)(smem + FOFF_B + ((ks*16 + wn*4 + ni) << 10) + (lane << 4));
            #pragma unroll
            for (int mi = 0; mi < 4; ++mi) {
                const short8 af = *(const short8*)(smem + FOFF_A + ((ks*8 + wm*4 + mi) << 10) + (lane << 4));
                #pragma unroll
                for (int ni = 0; ni < 4; ++ni)
                    acc[mi][ni] = __builtin_amdgcn_mfma_f32_16x16x32_bf16(af, bf[ni], acc[mi][ni], 0, 0, 0);
            }
        }
        __syncthreads();
    }
    const size_t qk_off = (size_t)isK * ((size_t)NB*NL*NH*NR);
    const int row_l = (lane >> 4) * 4, col_r = lane & 15;
    #pragma unroll
    for (int mi = 0; mi < 4; ++mi) {
        const int lg = l0 + wm*64 + mi*16 + row_l;
        #pragma unroll
        for (int ni = 0; ni < 4; ++ni) {
            const int rg = wn*64 + ni*16 + col_r;
            const f32x4 v = acc[mi][ni];
            #pragma unroll
            for (int q = 0; q < 4; ++q)
                out[qk_off + ((size_t)((b*NL + lg + q)*NH + h))*NR + rg] = v[q];
        }
    }
}

extern "C" void kernel_launch(void* const* d_in, const int* in_sizes, int n_in,
                              void* d_out, int out_size, void* d_ws, size_t ws_size,
                              hipStream_t stream) {
    const float* queries = (const float*)d_in[0];
    const float* keys    = (const float*)d_in[1];
    const float* z       = (const float*)d_in[2];
    const float* freqs   = (const float*)d_in[3];
    const float* offsets = (const float*)d_in[4];
    const float* gains   = (const float*)d_in[5];
    float* out = (float*)d_out;

    if (ws_size >= WS_NEEDED) {
        unsigned char* bpack = (unsigned char*)d_ws;
        spe_prep<<<dim3(NCH, NB*NH), 256, 0, stream>>>(z, gains, bpack);
        spe_main<<<dim3(NL/64, NB*NH), 512, 0, stream>>>(queries, keys, freqs, offsets, bpack, out);
    } else {
        spe_mfma_fb<<<dim3(NL/BM, NB*NH, 2), 512, 0, stream>>>(queries, keys, z, freqs, offsets, gains, out);
    }
}